// Round 9
// baseline (796.640 us; speedup 1.0000x reference)
//
#include <hip/hip_runtime.h>
#include <math.h>

#define Bb 2
#define Ll 2048
#define Dm 1024
#define Ns 16
#define Rr 64
#define Ee 96          // DT_RANK + 2*D_STATE
#define XPS 8          // K-splits for xproj GEMM (K-slice = 128)
#define BLK (Bb*Ll)    // 4096 rows
#define NTHR 256
#define CH 64          // chunks per sequence
#define CL 32          // chunk length

// ========== Kernel 1: xproj split-K GEMM. BM=64, k-major LDS, b128/b64 fragment reads ==========
// grid = 64 mtiles x 8 ksplits = 512 blocks. K-slice 128 staged in 4 sub-chunks of 32.
__global__ void __launch_bounds__(NTHR)
k_xproj(const float* __restrict__ x, const float* __restrict__ xw,
        float* __restrict__ xp_part) {
    __shared__ float xsT[32 * 68];    // [k][row]
    __shared__ float wT [32 * 100];   // [k][e]
    int bx = blockIdx.x;
    int ks = bx & 7, mt = bx >> 3;
    int i0 = mt * 64;
    int tid = threadIdx.x;
    int tx = tid & 15, ty = tid >> 4;    // thread tile: 4 rows x 6 cols

    float acc[4][6];
#pragma unroll
    for (int ii = 0; ii < 4; ++ii)
#pragma unroll
        for (int jj = 0; jj < 6; ++jj) acc[ii][jj] = 0.f;

    for (int kc = 0; kc < 4; ++kc) {
        int k0 = ks * 128 + kc * 32;
        for (int t = tid; t < 512; t += NTHR) {          // x: 64 rows x 32 k
            int r = t >> 3, c = (t & 7) * 4;
            float4 v = *(const float4*)(x + (size_t)(i0 + r) * Dm + k0 + c);
            xsT[(c+0)*68 + r] = v.x; xsT[(c+1)*68 + r] = v.y;
            xsT[(c+2)*68 + r] = v.z; xsT[(c+3)*68 + r] = v.w;
        }
        for (int t = tid; t < 768; t += NTHR) {          // w: 96 rows x 32 k
            int r = t >> 3, c = (t & 7) * 4;
            float4 v = *(const float4*)(xw + (size_t)r * Dm + k0 + c);
            wT[(c+0)*100 + r] = v.x; wT[(c+1)*100 + r] = v.y;
            wT[(c+2)*100 + r] = v.z; wT[(c+3)*100 + r] = v.w;
        }
        __syncthreads();
#pragma unroll 8
        for (int k = 0; k < 32; ++k) {
            float xv[4], wv[6];
            *(float4*)xv     = *(const float4*)(xsT + k*68 + ty*4);
            *(float2*)(wv)   = *(const float2*)(wT + k*100 + tx*6);
            *(float2*)(wv+2) = *(const float2*)(wT + k*100 + tx*6 + 2);
            *(float2*)(wv+4) = *(const float2*)(wT + k*100 + tx*6 + 4);
#pragma unroll
            for (int ii = 0; ii < 4; ++ii)
#pragma unroll
                for (int jj = 0; jj < 6; ++jj)
                    acc[ii][jj] = fmaf(xv[ii], wv[jj], acc[ii][jj]);
        }
        __syncthreads();
    }
#pragma unroll
    for (int ii = 0; ii < 4; ++ii)
#pragma unroll
        for (int jj = 0; jj < 6; ++jj)
            xp_part[((size_t)ks * BLK + (i0 + ty*4 + ii)) * Ee + tx*6 + jj] = acc[ii][jj];
}

// ========== Kernel 2: reduce K-splits -> xpR [bl][64], xpBC [bl][32]; zero lookback flags ==========
__global__ void __launch_bounds__(NTHR)
k_prep(const float* __restrict__ xp_part, float* __restrict__ xpR,
       float* __restrict__ xpBC, int* __restrict__ flags) {
    int gid = blockIdx.x * NTHR + threadIdx.x;     // 4096*24 = 98304 exactly
    if (gid < 8 * CH) flags[gid] = 0;              // 512 flags, re-zeroed every call
    int r = gid / 24, c4 = gid % 24;
    float4 s = make_float4(0.f, 0.f, 0.f, 0.f);
#pragma unroll
    for (int i = 0; i < XPS; ++i) {
        float4 v = *(const float4*)(xp_part + ((size_t)i * BLK + r) * Ee + c4 * 4);
        s.x += v.x; s.y += v.y; s.z += v.z; s.w += v.w;
    }
    if (c4 < 16) *(float4*)(xpR  + (size_t)r * Rr + c4 * 4)        = s;
    else         *(float4*)(xpBC + (size_t)r * 32 + (c4 - 16) * 4) = s;
}

// ========== Kernel 3: delta[bl][d] = softplus(xpR[bl] . dtw[d] + dtb[d]) ==========
// BM=64, BN=64 -> 1024 blocks. k-major LDS, b128 fragment reads. (r7-proven variant)
__global__ void __launch_bounds__(NTHR)
k_delta(const float* __restrict__ xpR, const float* __restrict__ dtw,
        const float* __restrict__ dtb, float* __restrict__ delta) {
    __shared__ float xsT[64 * 68];    // [k][row]
    __shared__ float wT [64 * 68];    // [k][d-local]
    int bx = blockIdx.x;
    int nt = bx & 15, mt = bx >> 4;
    int i0 = mt * 64, j0 = nt * 64;
    int tid = threadIdx.x, tx = tid & 15, ty = tid >> 4;

    for (int t = tid; t < 1024; t += NTHR) {
        int r = t >> 4, c = (t & 15) * 4;
        float4 v = *(const float4*)(xpR + (size_t)(i0 + r) * Rr + c);
        xsT[(c+0)*68 + r] = v.x; xsT[(c+1)*68 + r] = v.y;
        xsT[(c+2)*68 + r] = v.z; xsT[(c+3)*68 + r] = v.w;
        float4 w = *(const float4*)(dtw + (size_t)(j0 + r) * Rr + c);
        wT[(c+0)*68 + r] = w.x; wT[(c+1)*68 + r] = w.y;
        wT[(c+2)*68 + r] = w.z; wT[(c+3)*68 + r] = w.w;
    }
    __syncthreads();

    float acc[4][4];
#pragma unroll
    for (int ii = 0; ii < 4; ++ii)
#pragma unroll
        for (int jj = 0; jj < 4; ++jj) acc[ii][jj] = 0.f;
#pragma unroll 8
    for (int k = 0; k < 64; ++k) {
        float xv[4], wv[4];
        *(float4*)xv = *(const float4*)(xsT + k*68 + ty*4);
        *(float4*)wv = *(const float4*)(wT  + k*68 + tx*4);
#pragma unroll
        for (int ii = 0; ii < 4; ++ii)
#pragma unroll
            for (int jj = 0; jj < 4; ++jj)
                acc[ii][jj] = fmaf(xv[ii], wv[jj], acc[ii][jj]);
    }
    int d0 = j0 + tx * 4;
    float4 bias = *(const float4*)(dtb + d0);
#pragma unroll
    for (int ii = 0; ii < 4; ++ii) {
        int bl = i0 + ty*4 + ii;
        float z0 = acc[ii][0] + bias.x, z1 = acc[ii][1] + bias.y;
        float z2 = acc[ii][2] + bias.z, z3 = acc[ii][3] + bias.w;
        float4 o;
        o.x = fmaxf(z0, 0.f) + log1pf(__expf(-fabsf(z0)));
        o.y = fmaxf(z1, 0.f) + log1pf(__expf(-fabsf(z1)));
        o.z = fmaxf(z2, 0.f) + log1pf(__expf(-fabsf(z2)));
        o.w = fmaxf(z3, 0.f) + log1pf(__expf(-fabsf(z3)));
        *(float4*)(delta + (size_t)bl * Dm + d0) = o;
    }
}

// ---- helper: load A row into regs ----
__device__ inline void load_a(const float* __restrict__ A_log, int d, float* a) {
    const float4* Ap = (const float4*)(A_log + (size_t)d * Ns);
    float4 a0 = Ap[0], a1 = Ap[1], a2 = Ap[2], a3 = Ap[3];
    float tmp[Ns] = {a0.x,a0.y,a0.z,a0.w, a1.x,a1.y,a1.z,a1.w,
                     a2.x,a2.y,a2.z,a2.w, a3.x,a3.y,a3.z,a3.w};
#pragma unroll
    for (int n = 0; n < Ns; ++n) a[n] = -__expf(tmp[n]);
}

// ========== Kernel 4: single-pass chunked scan with decoupled look-back ==========
// grid = 8 slices (b*4+dblk) x CH chunks = 512 blocks. NO LDS; VGPR-capped for >=2 blocks/CU
// => all 512 blocks co-resident => look-back progress independent of dispatch order.
// Cross-XCD coherence: data via volatile (LLC-coherent) loads/stores; flags via agent-scope atomics.
__global__ void __launch_bounds__(NTHR, 2)
k_scan_lb(const float* __restrict__ delta, const float* __restrict__ x,
          const float* __restrict__ xpBC, const float* __restrict__ A_log,
          const float* __restrict__ Dp,
          float* __restrict__ Ec, float* __restrict__ Sc, float* __restrict__ Hinc,
          int* __restrict__ flags, float* __restrict__ out) {
    int bx = blockIdx.x;
    int slice = bx >> 6, c = bx & (CH - 1);
    int b = slice >> 2, dblk = slice & 3;
    int tid = threadIdx.x;
    int d = dblk * 256 + tid;
    int row0 = b * Ll + c * CL;

    float a[Ns];
    load_a(A_log, d, a);
    float Dval = Dp[d];

    // ---- phase 1: local scan (h0 = 0); keep dl/xv in registers for phase 3 ----
    float dl[CL], xv[CL], h[Ns];
#pragma unroll
    for (int n = 0; n < Ns; ++n) h[n] = 0.f;
    float sd = 0.f;
#pragma unroll
    for (int t = 0; t < CL; ++t) {
        size_t row = (size_t)(row0 + t);
        dl[t] = delta[row * Dm + d];
        xv[t] = x[row * Dm + d];
        const float* bp = xpBC + row * 32;           // block-uniform -> scalar loads
        float4 B0 = *(const float4*)(bp + 0),  B1 = *(const float4*)(bp + 4);
        float4 B2 = *(const float4*)(bp + 8),  B3 = *(const float4*)(bp + 12);
        float Bv[Ns] = {B0.x,B0.y,B0.z,B0.w, B1.x,B1.y,B1.z,B1.w,
                        B2.x,B2.y,B2.z,B2.w, B3.x,B3.y,B3.z,B3.w};
        float dx = dl[t] * xv[t];
        sd += dl[t];
#pragma unroll
        for (int n = 0; n < Ns; ++n)
            h[n] = fmaf(__expf(dl[t] * a[n]), h[n], dx * Bv[n]);
    }

    size_t pbase = ((size_t)(b * CH + c) * Dm + d);
    float h_in[Ns];

    if (c == 0) {
        // inclusive == local; publish tier-2 directly
        volatile float* vH = (volatile float*)(Hinc + pbase * Ns);
#pragma unroll
        for (int n = 0; n < Ns; ++n) vH[n] = h[n];
        __threadfence();
        __syncthreads();
        if (tid == 0)
            __hip_atomic_store(&flags[bx], 2, __ATOMIC_RELEASE, __HIP_MEMORY_SCOPE_AGENT);
#pragma unroll
        for (int n = 0; n < Ns; ++n) h_in[n] = 0.f;
    } else {
        // publish aggregate (tier 1)
        {
            volatile float* vE = (volatile float*)(Ec + pbase * Ns);
#pragma unroll
            for (int n = 0; n < Ns; ++n) vE[n] = h[n];
            ((volatile float*)Sc)[pbase] = sd;
            __threadfence();
            __syncthreads();
            if (tid == 0)
                __hip_atomic_store(&flags[bx], 1, __ATOMIC_RELEASE, __HIP_MEMORY_SCOPE_AGENT);
        }
        // look-back
        float accP[Ns], accE[Ns];
#pragma unroll
        for (int n = 0; n < Ns; ++n) { accP[n] = 1.f; accE[n] = 0.f; }
        int cp = c - 1;
        while (true) {
            int fi = (slice << 6) + cp;
            int f;
            while ((f = __hip_atomic_load(&flags[fi], __ATOMIC_ACQUIRE,
                                          __HIP_MEMORY_SCOPE_AGENT)) == 0)
                __builtin_amdgcn_s_sleep(2);
            size_t qbase = ((size_t)(b * CH + cp) * Dm + d);
            if (f == 1) {
                float S = ((volatile const float*)Sc)[qbase];
                volatile const float* vE = (volatile const float*)(Ec + qbase * Ns);
#pragma unroll
                for (int n = 0; n < Ns; ++n) {
                    accE[n] = fmaf(accP[n], vE[n], accE[n]);
                    accP[n] *= __expf(a[n] * S);
                }
                --cp;      // flags[slice*CH+0] is always 2, so cp never goes below 0
            } else {
                volatile const float* vH = (volatile const float*)(Hinc + qbase * Ns);
#pragma unroll
                for (int n = 0; n < Ns; ++n)
                    accE[n] = fmaf(accP[n], vH[n], accE[n]);
                break;
            }
        }
#pragma unroll
        for (int n = 0; n < Ns; ++n) h_in[n] = accE[n];
        // publish inclusive (tier 2) for successors
        if (c < CH - 1) {
            volatile float* vH = (volatile float*)(Hinc + pbase * Ns);
#pragma unroll
            for (int n = 0; n < Ns; ++n)
                vH[n] = fmaf(__expf(a[n] * sd), h_in[n], h[n]);
            __threadfence();
            __syncthreads();
            if (tid == 0)
                __hip_atomic_store(&flags[bx], 2, __ATOMIC_RELEASE, __HIP_MEMORY_SCOPE_AGENT);
        }
    }

    // ---- phase 3: re-scan from true h_in using registered dl/xv, emit y ----
#pragma unroll
    for (int n = 0; n < Ns; ++n) h[n] = h_in[n];
#pragma unroll
    for (int t = 0; t < CL; ++t) {
        size_t row = (size_t)(row0 + t);
        const float* bp = xpBC + row * 32;
        float4 B0 = *(const float4*)(bp + 0),  B1 = *(const float4*)(bp + 4);
        float4 B2 = *(const float4*)(bp + 8),  B3 = *(const float4*)(bp + 12);
        float4 C0 = *(const float4*)(bp + 16), C1 = *(const float4*)(bp + 20);
        float4 C2 = *(const float4*)(bp + 24), C3 = *(const float4*)(bp + 28);
        float Bv[Ns] = {B0.x,B0.y,B0.z,B0.w, B1.x,B1.y,B1.z,B1.w,
                        B2.x,B2.y,B2.z,B2.w, B3.x,B3.y,B3.z,B3.w};
        float Cv[Ns] = {C0.x,C0.y,C0.z,C0.w, C1.x,C1.y,C1.z,C1.w,
                        C2.x,C2.y,C2.z,C2.w, C3.x,C3.y,C3.z,C3.w};
        float dx = dl[t] * xv[t];
        float y = 0.f;
#pragma unroll
        for (int n = 0; n < Ns; ++n) {
            h[n] = fmaf(__expf(dl[t] * a[n]), h[n], dx * Bv[n]);
            y = fmaf(h[n], Cv[n], y);
        }
        out[row * Dm + d] = fmaf(xv[t], Dval, y);
    }
}

extern "C" void kernel_launch(void* const* d_in, const int* in_sizes, int n_in,
                              void* d_out, int out_size, void* d_ws, size_t ws_size,
                              hipStream_t stream) {
    const float* x     = (const float*)d_in[0];
    const float* A_log = (const float*)d_in[1];
    const float* Dp    = (const float*)d_in[2];
    const float* xw    = (const float*)d_in[3];
    const float* dtw   = (const float*)d_in[4];
    const float* dtb   = (const float*)d_in[5];
    float* out = (float*)d_out;
    float* ws  = (float*)d_ws;

    // workspace layout (floats), ~48 MB total:
    float* xpR     = ws;                          //   262,144
    float* xpBC    = xpR     + 262144;            //   131,072
    float* delta   = xpBC    + 131072;            // 4,194,304
    float* Ec      = delta   + 4194304;           // 2,097,152 (2*64*1024*16)
    float* Sc      = Ec      + 2097152;           //   131,072
    float* Hinc    = Sc      + 131072;            // 2,097,152
    float* xp_part = Hinc    + 2097152;           // 3,145,728 (8 * 393216)
    int*   flags   = (int*)(xp_part + 3145728);   //       512 ints

    k_xproj  <<<dim3(512),  dim3(NTHR), 0, stream>>>(x, xw, xp_part);
    k_prep   <<<dim3(384),  dim3(NTHR), 0, stream>>>(xp_part, xpR, xpBC, flags);
    k_delta  <<<dim3(1024), dim3(NTHR), 0, stream>>>(xpR, dtw, dtb, delta);
    k_scan_lb<<<dim3(512),  dim3(NTHR), 0, stream>>>(delta, x, xpBC, A_log, Dp,
                                                     Ec, Sc, Hinc, flags, out);
}

// Round 10
// 179.656 us; speedup vs baseline: 4.4343x; 4.4343x over previous
//
#include <hip/hip_runtime.h>
#include <math.h>

#define Bb 2
#define Ll 2048
#define Dm 1024
#define Ns 16
#define Rr 64
#define Ee 96          // DT_RANK + 2*D_STATE
#define XPS 8          // K-splits for xproj GEMM (K-slice = 128)
#define BLK (Bb*Ll)    // 4096 rows
#define NTHR 256
#define CH 64          // chunks
#define CL 32          // chunk length

// ========== Kernel 1: xproj split-K GEMM, k-major LDS, software-pipelined staging ==========
// grid = 64 mtiles x 8 ksplits = 512 blocks. K-slice 128 in 4 sub-chunks of 32, reg-prefetched.
__global__ void __launch_bounds__(NTHR)
k_xproj(const float* __restrict__ x, const float* __restrict__ xw,
        float* __restrict__ xp_part) {
    __shared__ float xsT[32 * 68];    // [k][row]
    __shared__ float wT [32 * 100];   // [k][e]
    int bx = blockIdx.x;
    int ks = bx & 7, mt = bx >> 3;
    int i0 = mt * 64;
    int tid = threadIdx.x;
    int tx = tid & 15, ty = tid >> 4;    // thread tile: 4 rows x 6 cols

    // fixed staging assignment: x -> 2 float4s, w -> 3 float4s per thread
    int xr0 = tid >> 3,        xc0 = (tid & 7) * 4;          // x task tid
    int xr1 = (tid + 256) >> 3, xc1 = ((tid + 256) & 7) * 4; // x task tid+256
    int wr0 = tid >> 3,        wc0 = (tid & 7) * 4;
    int wr1 = (tid + 256) >> 3, wc1 = ((tid + 256) & 7) * 4;
    int wr2 = (tid + 512) >> 3, wc2 = ((tid + 512) & 7) * 4;

    float acc[4][6];
#pragma unroll
    for (int ii = 0; ii < 4; ++ii)
#pragma unroll
        for (int jj = 0; jj < 6; ++jj) acc[ii][jj] = 0.f;

    float4 xa, xb, wa, wb, wc;
    {   // prefetch kc = 0
        int k0 = ks * 128;
        xa = *(const float4*)(x  + (size_t)(i0 + xr0) * Dm + k0 + xc0);
        xb = *(const float4*)(x  + (size_t)(i0 + xr1) * Dm + k0 + xc1);
        wa = *(const float4*)(xw + (size_t)wr0 * Dm + k0 + wc0);
        wb = *(const float4*)(xw + (size_t)wr1 * Dm + k0 + wc1);
        wc = *(const float4*)(xw + (size_t)wr2 * Dm + k0 + wc2);
    }
    for (int kc = 0; kc < 4; ++kc) {
        // commit staged regs -> LDS
        xsT[(xc0+0)*68 + xr0] = xa.x; xsT[(xc0+1)*68 + xr0] = xa.y;
        xsT[(xc0+2)*68 + xr0] = xa.z; xsT[(xc0+3)*68 + xr0] = xa.w;
        xsT[(xc1+0)*68 + xr1] = xb.x; xsT[(xc1+1)*68 + xr1] = xb.y;
        xsT[(xc1+2)*68 + xr1] = xb.z; xsT[(xc1+3)*68 + xr1] = xb.w;
        wT[(wc0+0)*100 + wr0] = wa.x; wT[(wc0+1)*100 + wr0] = wa.y;
        wT[(wc0+2)*100 + wr0] = wa.z; wT[(wc0+3)*100 + wr0] = wa.w;
        wT[(wc1+0)*100 + wr1] = wb.x; wT[(wc1+1)*100 + wr1] = wb.y;
        wT[(wc1+2)*100 + wr1] = wb.z; wT[(wc1+3)*100 + wr1] = wb.w;
        wT[(wc2+0)*100 + wr2] = wc.x; wT[(wc2+1)*100 + wr2] = wc.y;
        wT[(wc2+2)*100 + wr2] = wc.z; wT[(wc2+3)*100 + wr2] = wc.w;
        __syncthreads();
        if (kc < 3) {   // prefetch next sub-chunk during compute
            int k0 = ks * 128 + (kc + 1) * 32;
            xa = *(const float4*)(x  + (size_t)(i0 + xr0) * Dm + k0 + xc0);
            xb = *(const float4*)(x  + (size_t)(i0 + xr1) * Dm + k0 + xc1);
            wa = *(const float4*)(xw + (size_t)wr0 * Dm + k0 + wc0);
            wb = *(const float4*)(xw + (size_t)wr1 * Dm + k0 + wc1);
            wc = *(const float4*)(xw + (size_t)wr2 * Dm + k0 + wc2);
        }
#pragma unroll 8
        for (int k = 0; k < 32; ++k) {
            float xv[4], wv[6];
            *(float4*)xv     = *(const float4*)(xsT + k*68 + ty*4);
            *(float2*)(wv)   = *(const float2*)(wT + k*100 + tx*6);
            *(float2*)(wv+2) = *(const float2*)(wT + k*100 + tx*6 + 2);
            *(float2*)(wv+4) = *(const float2*)(wT + k*100 + tx*6 + 4);
#pragma unroll
            for (int ii = 0; ii < 4; ++ii)
#pragma unroll
                for (int jj = 0; jj < 6; ++jj)
                    acc[ii][jj] = fmaf(xv[ii], wv[jj], acc[ii][jj]);
        }
        __syncthreads();
    }
#pragma unroll
    for (int ii = 0; ii < 4; ++ii)
#pragma unroll
        for (int jj = 0; jj < 6; ++jj)
            xp_part[((size_t)ks * BLK + (i0 + ty*4 + ii)) * Ee + tx*6 + jj] = acc[ii][jj];
}

// ========== Kernel 2: reduce K-splits -> xpR [bl][64], xpBC [bl][32] ==========
__global__ void __launch_bounds__(NTHR)
k_prep(const float* __restrict__ xp_part, float* __restrict__ xpR,
       float* __restrict__ xpBC) {
    int gid = blockIdx.x * NTHR + threadIdx.x;     // 4096*24 = 98304 exactly
    int r = gid / 24, c4 = gid % 24;
    float4 s = make_float4(0.f, 0.f, 0.f, 0.f);
#pragma unroll
    for (int i = 0; i < XPS; ++i) {
        float4 v = *(const float4*)(xp_part + ((size_t)i * BLK + r) * Ee + c4 * 4);
        s.x += v.x; s.y += v.y; s.z += v.z; s.w += v.w;
    }
    if (c4 < 16) *(float4*)(xpR  + (size_t)r * Rr + c4 * 4)        = s;
    else         *(float4*)(xpBC + (size_t)r * 32 + (c4 - 16) * 4) = s;
}

// ========== Kernel 3: delta[bl][d] = softplus(xpR[bl] . dtw[d] + dtb[d]) ==========
// BM=64, BN=64 -> 1024 blocks. k-major LDS, b128 fragment reads. (r7-proven)
__global__ void __launch_bounds__(NTHR)
k_delta(const float* __restrict__ xpR, const float* __restrict__ dtw,
        const float* __restrict__ dtb, float* __restrict__ delta) {
    __shared__ float xsT[64 * 68];
    __shared__ float wT [64 * 68];
    int bx = blockIdx.x;
    int nt = bx & 15, mt = bx >> 4;
    int i0 = mt * 64, j0 = nt * 64;
    int tid = threadIdx.x, tx = tid & 15, ty = tid >> 4;

    for (int t = tid; t < 1024; t += NTHR) {
        int r = t >> 4, c = (t & 15) * 4;
        float4 v = *(const float4*)(xpR + (size_t)(i0 + r) * Rr + c);
        xsT[(c+0)*68 + r] = v.x; xsT[(c+1)*68 + r] = v.y;
        xsT[(c+2)*68 + r] = v.z; xsT[(c+3)*68 + r] = v.w;
        float4 w = *(const float4*)(dtw + (size_t)(j0 + r) * Rr + c);
        wT[(c+0)*68 + r] = w.x; wT[(c+1)*68 + r] = w.y;
        wT[(c+2)*68 + r] = w.z; wT[(c+3)*68 + r] = w.w;
    }
    __syncthreads();

    float acc[4][4];
#pragma unroll
    for (int ii = 0; ii < 4; ++ii)
#pragma unroll
        for (int jj = 0; jj < 4; ++jj) acc[ii][jj] = 0.f;
#pragma unroll 8
    for (int k = 0; k < 64; ++k) {
        float xv[4], wv[4];
        *(float4*)xv = *(const float4*)(xsT + k*68 + ty*4);
        *(float4*)wv = *(const float4*)(wT  + k*68 + tx*4);
#pragma unroll
        for (int ii = 0; ii < 4; ++ii)
#pragma unroll
            for (int jj = 0; jj < 4; ++jj)
                acc[ii][jj] = fmaf(xv[ii], wv[jj], acc[ii][jj]);
    }
    int d0 = j0 + tx * 4;
    float4 bias = *(const float4*)(dtb + d0);
#pragma unroll
    for (int ii = 0; ii < 4; ++ii) {
        int bl = i0 + ty*4 + ii;
        float z0 = acc[ii][0] + bias.x, z1 = acc[ii][1] + bias.y;
        float z2 = acc[ii][2] + bias.z, z3 = acc[ii][3] + bias.w;
        float4 o;
        o.x = fmaxf(z0, 0.f) + log1pf(__expf(-fabsf(z0)));
        o.y = fmaxf(z1, 0.f) + log1pf(__expf(-fabsf(z1)));
        o.z = fmaxf(z2, 0.f) + log1pf(__expf(-fabsf(z2)));
        o.w = fmaxf(z3, 0.f) + log1pf(__expf(-fabsf(z3)));
        *(float4*)(delta + (size_t)bl * Dm + d0) = o;
    }
}

// ========== Kernel 4: per-chunk local scan, SPLIT STATES (8/thread) -> Ec, Sc ==========
// grid = Bb*CH*8 = 1024 blocks. waves 0-1: states 0-7, waves 2-3: states 8-15 (same 128 d's).
__global__ void __launch_bounds__(NTHR)
k_scan_part(const float* __restrict__ delta, const float* __restrict__ x,
            const float* __restrict__ xpBC, const float* __restrict__ A_log,
            float* __restrict__ Ec, float* __restrict__ Sc) {
    int bx = blockIdx.x;
    int dblk = bx & 7, chunk = (bx >> 3) & (CH - 1), b = bx >> 9;
    int tid = threadIdx.x;
    int nh = tid >> 7, dl_ = tid & 127;
    int d = dblk * 128 + dl_;
    int n0 = nh * 8;
    int row0 = b * Ll + chunk * CL;

    float a[8], h[8];
    {
        const float4* Ap = (const float4*)(A_log + (size_t)d * Ns + n0);
        float4 a0 = Ap[0], a1 = Ap[1];
        float tmp[8] = {a0.x,a0.y,a0.z,a0.w, a1.x,a1.y,a1.z,a1.w};
#pragma unroll
        for (int n = 0; n < 8; ++n) { a[n] = -__expf(tmp[n]); h[n] = 0.f; }
    }
    float sd = 0.f;
#pragma unroll 4
    for (int t = 0; t < CL; ++t) {
        size_t row = (size_t)(row0 + t);
        float dl = delta[row * Dm + d];
        float xv = x[row * Dm + d];
        const float* bp = xpBC + row * 32 + n0;     // block+wave-uniform -> scalar loads
        float4 B0 = *(const float4*)(bp + 0), B1 = *(const float4*)(bp + 4);
        float Bv[8] = {B0.x,B0.y,B0.z,B0.w, B1.x,B1.y,B1.z,B1.w};
        float dx = dl * xv;
        sd += dl;
#pragma unroll
        for (int n = 0; n < 8; ++n)
            h[n] = fmaf(__expf(dl * a[n]), h[n], dx * Bv[n]);
    }
    size_t base = ((size_t)b * CH + chunk) * Dm + d;
    float4* Ep = (float4*)(Ec + base * Ns + n0);
    Ep[0] = make_float4(h[0], h[1], h[2], h[3]);
    Ep[1] = make_float4(h[4], h[5], h[6], h[7]);
    if (nh == 0) Sc[base] = sd;
}

// ========== Kernel 5: sequential combine over chunks -> Hin ==========
__global__ void __launch_bounds__(NTHR)
k_combine(const float* __restrict__ Ec, const float* __restrict__ Sc,
          const float* __restrict__ A_log, float* __restrict__ Hin) {
    int gid = blockIdx.x * NTHR + threadIdx.x;   // < Bb*Dm*Ns = 32768
    int n = gid & (Ns - 1);
    int d = (gid >> 4) & (Dm - 1);
    int b = gid >> 14;
    float a = -__expf(A_log[d * Ns + n]);
    float h = 0.f;
#pragma unroll 8
    for (int c = 0; c < CH; ++c) {
        size_t base = ((size_t)b * CH + c) * Dm + d;
        Hin[base * Ns + n] = h;
        float P = __expf(a * Sc[base]);
        h = fmaf(P, h, Ec[base * Ns + n]);
    }
}

// ========== Kernel 6: full scan, SPLIT STATES; LDS merge of half-sums; emit y ==========
__global__ void __launch_bounds__(NTHR)
k_scan_full(const float* __restrict__ delta, const float* __restrict__ x,
            const float* __restrict__ xpBC, const float* __restrict__ A_log,
            const float* __restrict__ Dp, const float* __restrict__ Hin,
            float* __restrict__ out) {
    __shared__ float ybuf[CL * 128];             // 16 KB: [t][d_local]
    int bx = blockIdx.x;
    int dblk = bx & 7, chunk = (bx >> 3) & (CH - 1), b = bx >> 9;
    int tid = threadIdx.x;
    int nh = tid >> 7, dl_ = tid & 127;
    int d = dblk * 128 + dl_;
    int n0 = nh * 8;
    int row0 = b * Ll + chunk * CL;

    float a[8], h[8];
    {
        const float4* Ap = (const float4*)(A_log + (size_t)d * Ns + n0);
        float4 a0 = Ap[0], a1 = Ap[1];
        float tmp[8] = {a0.x,a0.y,a0.z,a0.w, a1.x,a1.y,a1.z,a1.w};
#pragma unroll
        for (int n = 0; n < 8; ++n) a[n] = -__expf(tmp[n]);
    }
    size_t base = ((size_t)b * CH + chunk) * Dm + d;
    {
        const float4* Hp = (const float4*)(Hin + base * Ns + n0);
        float4 h0 = Hp[0], h1 = Hp[1];
        h[0]=h0.x; h[1]=h0.y; h[2]=h0.z; h[3]=h0.w;
        h[4]=h1.x; h[5]=h1.y; h[6]=h1.z; h[7]=h1.w;
    }
    float Dval = Dp[d];

    float yp[CL];
#pragma unroll 4
    for (int t = 0; t < CL; ++t) {
        size_t row = (size_t)(row0 + t);
        float dl = delta[row * Dm + d];
        float xv = x[row * Dm + d];
        const float* bp = xpBC + row * 32;
        float4 B0 = *(const float4*)(bp + n0),      B1 = *(const float4*)(bp + n0 + 4);
        float4 C0 = *(const float4*)(bp + 16 + n0), C1 = *(const float4*)(bp + 20 + n0);
        float Bv[8] = {B0.x,B0.y,B0.z,B0.w, B1.x,B1.y,B1.z,B1.w};
        float Cv[8] = {C0.x,C0.y,C0.z,C0.w, C1.x,C1.y,C1.z,C1.w};
        float dx = dl * xv;
        float y = 0.f;
#pragma unroll
        for (int n = 0; n < 8; ++n) {
            h[n] = fmaf(__expf(dl * a[n]), h[n], dx * Bv[n]);
            y = fmaf(h[n], Cv[n], y);
        }
        yp[t] = (nh == 0) ? fmaf(xv, Dval, y) : y;   // fold D-skip into half 0
    }
    // merge halves: half1 stages its partials, half0 adds and writes out
    if (nh == 1) {
#pragma unroll
        for (int t = 0; t < CL; ++t) ybuf[t * 128 + dl_] = yp[t];
    }
    __syncthreads();
    if (nh == 0) {
#pragma unroll 4
        for (int t = 0; t < CL; ++t) {
            size_t row = (size_t)(row0 + t);
            out[row * Dm + d] = yp[t] + ybuf[t * 128 + dl_];
        }
    }
}

extern "C" void kernel_launch(void* const* d_in, const int* in_sizes, int n_in,
                              void* d_out, int out_size, void* d_ws, size_t ws_size,
                              hipStream_t stream) {
    const float* x     = (const float*)d_in[0];
    const float* A_log = (const float*)d_in[1];
    const float* Dp    = (const float*)d_in[2];
    const float* xw    = (const float*)d_in[3];
    const float* dtw   = (const float*)d_in[4];
    const float* dtb   = (const float*)d_in[5];
    float* out = (float*)d_out;
    float* ws  = (float*)d_ws;

    // workspace layout (floats), ~48 MB total, no aliasing:
    float* xpR     = ws;                          //   262,144
    float* xpBC    = xpR     + 262144;            //   131,072
    float* delta   = xpBC    + 131072;            // 4,194,304
    float* Ec      = delta   + 4194304;           // 2,097,152
    float* Sc      = Ec      + 2097152;           //   131,072
    float* Hin     = Sc      + 131072;            // 2,097,152
    float* xp_part = Hin     + 2097152;           // 3,145,728

    k_xproj    <<<dim3(512),  dim3(NTHR), 0, stream>>>(x, xw, xp_part);
    k_prep     <<<dim3(384),  dim3(NTHR), 0, stream>>>(xp_part, xpR, xpBC);
    k_delta    <<<dim3(1024), dim3(NTHR), 0, stream>>>(xpR, dtw, dtb, delta);
    k_scan_part<<<dim3(1024), dim3(NTHR), 0, stream>>>(delta, x, xpBC, A_log, Ec, Sc);
    k_combine  <<<dim3(128),  dim3(NTHR), 0, stream>>>(Ec, Sc, A_log, Hin);
    k_scan_full<<<dim3(1024), dim3(NTHR), 0, stream>>>(delta, x, xpBC, A_log, Dp, Hin, out);
}